// Round 2
// baseline (280.275 us; speedup 1.0000x reference)
//
#include <hip/hip_runtime.h>
#include <hip/hip_bf16.h>

typedef __bf16 bf16;
typedef __attribute__((ext_vector_type(8))) __bf16 bf16x8;
typedef __attribute__((ext_vector_type(4))) __bf16 bf16x4;
typedef __attribute__((ext_vector_type(4))) float f32x4;

#define B_   2
#define L_   2048
#define D_   1024
#define H_   16
#define HD_  64

__device__ __forceinline__ float fast_exp2(float x) {
  float e; asm("v_exp_f32 %0, %1" : "=v"(e) : "v"(x)); return e;
}

// async global->LDS, 16B per lane. LDS dest = wave-uniform base + lane*16.
__device__ __forceinline__ void gll16(const bf16* g, bf16* l) {
  __builtin_amdgcn_global_load_lds((const __attribute__((address_space(1))) void*)g,
                                   (__attribute__((address_space(3))) void*)l,
                                   16, 0, 0);
}

// ---------------- dtype + mask-layout detection ----------------
__global__ void detect_kernel(const unsigned short* __restrict__ q_u,
                              const unsigned char* __restrict__ m_u,
                              int* __restrict__ flags) {
  __shared__ int cnt, odd;
  if (threadIdx.x == 0) { cnt = 0; odd = 0; }
  __syncthreads();
  int c = 0, o = 0;
  for (int i = 0; i < 8; i++) {
    int idx = threadIdx.x * 8 + i;
    unsigned e = (q_u[idx] >> 7) & 0xFF;
    if (e >= 0x8F || (e > 0 && e <= 0x6F)) c++;   // wild exponent
    if ((idx & 3) && m_u[idx]) o = 1;             // nonzero odd byte -> int8 mask
  }
  atomicAdd(&cnt, c);
  if (o) atomicOr(&odd, 1);
  __syncthreads();
  if (threadIdx.x == 0) { flags[0] = (cnt > 128) ? 1 : 0; flags[1] = odd; }
}

// ---------------- canonicalize (7 tensors) + mask bit-pack, ONE launch ----------------
__device__ __forceinline__ void canon_body(const void* src, bf16* dst, int i, int f) {
  if (f) {
    const float4* s = (const float4*)src;
    float4 a = s[i / 4], b2 = s[i / 4 + 1];
    bf16x8 o;
    o[0] = (bf16)a.x;  o[1] = (bf16)a.y;  o[2] = (bf16)a.z;  o[3] = (bf16)a.w;
    o[4] = (bf16)b2.x; o[5] = (bf16)b2.y; o[6] = (bf16)b2.z; o[7] = (bf16)b2.w;
    *(bf16x8*)(dst + i) = o;
  } else {
    *(bf16x8*)(dst + i) = ((const bf16x8*)src)[i / 8];
  }
}

__global__ __launch_bounds__(256) void canon_pack(
    const void* xq, const void* xk, const void* xv,
    const void* Wq, const void* Wk, const void* Wv, const void* Wo,
    const void* mp,
    bf16* cxq, bf16* cxk, bf16* cxv,
    bf16* cWq, bf16* cWk, bf16* cWv, bf16* cWo,
    unsigned* __restrict__ bitsT,
    const int* __restrict__ flags) {
  int t = blockIdx.x;
  if (t >= 8192) {
    // ---- mask pack: bitsT[(kt*4096+row)*2+half], transposed layout ----
    int wid = (t - 8192) * 256 + threadIdx.x;   // one 32-bit word per thread
    unsigned v = 0;
    if (flags[1]) {                              // int8 layout
      const uchar4* p = (const uchar4*)mp;
#pragma unroll
      for (int c = 0; c < 8; c++) {
        uchar4 u = p[wid * 8 + c];
        v |= (u.x ? 1u : 0u) << (c * 4 + 0);
        v |= (u.y ? 1u : 0u) << (c * 4 + 1);
        v |= (u.z ? 1u : 0u) << (c * 4 + 2);
        v |= (u.w ? 1u : 0u) << (c * 4 + 3);
      }
    } else {                                     // int32 layout
      const int4* p = (const int4*)mp;
#pragma unroll
      for (int c = 0; c < 8; c++) {
        int4 u = p[wid * 8 + c];
        v |= (u.x ? 1u : 0u) << (c * 4 + 0);
        v |= (u.y ? 1u : 0u) << (c * 4 + 1);
        v |= (u.z ? 1u : 0u) << (c * 4 + 2);
        v |= (u.w ? 1u : 0u) << (c * 4 + 3);
      }
    }
    int row = wid >> 6, word = wid & 63;
    int kt = word >> 1, half = word & 1;
    bitsT[((size_t)kt * 4096 + row) * 2 + half] = v;
    return;
  }
  const int f = flags[0];
  const void* src; bf16* dst; int base;
  if (t < 2048)      { src = xq; dst = cxq; base = t * 2048; }
  else if (t < 4096) { src = xk; dst = cxk; base = (t - 2048) * 2048; }
  else if (t < 6144) { src = xv; dst = cxv; base = (t - 4096) * 2048; }
  else {
    int w = t - 6144, wi = w >> 9;
    base = (w & 511) * 2048;
    if (wi == 0)      { src = Wq; dst = cWq; }
    else if (wi == 1) { src = Wk; dst = cWk; }
    else if (wi == 2) { src = Wv; dst = cWv; }
    else              { src = Wo; dst = cWo; }
  }
  canon_body(src, dst, base + threadIdx.x * 8, f);
}

// ---------------- fused QKV NT GEMM, 128x128 tile ----------------
// z==0: Q scaled by 0.125*log2(e). z==1: K. z==2: V -> VT transposed per head.
__global__ __launch_bounds__(256) void gemm_qkv(
    const bf16* __restrict__ Aq, const bf16* __restrict__ Bq, bf16* __restrict__ Cq,
    const bf16* __restrict__ Ak, const bf16* __restrict__ Bk, bf16* __restrict__ Ck,
    const bf16* __restrict__ Av, const bf16* __restrict__ Bv, bf16* __restrict__ VT) {
  __shared__ bf16 smem[128 * 136];
  bf16* sA = smem;
  bf16* sB = smem + 4096;
  const int z = blockIdx.z;
  const bf16* A  = (z == 0) ? Aq : (z == 1) ? Ak : Av;
  const bf16* Bm = (z == 0) ? Bq : (z == 1) ? Bk : Bv;

  const int tid = threadIdx.x;
  const int w = tid >> 6, lane = tid & 63, qd = lane >> 4, r = lane & 15;
  const int wm = w >> 1, wn = w & 1;
  const int m0 = blockIdx.x * 128, n0 = blockIdx.y * 128;

  f32x4 acc[4][4];
#pragma unroll
  for (int i = 0; i < 4; i++)
#pragma unroll
    for (int j = 0; j < 4; j++) acc[i][j] = (f32x4){0.f, 0.f, 0.f, 0.f};

  for (int k0 = 0; k0 < 1024; k0 += 32) {
    __syncthreads();
#pragma unroll
    for (int p = 0; p < 2; p++) {
      int c = p * 256 + tid;
      gll16(A + (size_t)(m0 + (c >> 2)) * 1024 + k0 + (c & 3) * 8, sA + c * 8);
    }
#pragma unroll
    for (int p = 0; p < 2; p++) {
      int c = p * 256 + tid;
      gll16(Bm + (size_t)(n0 + (c >> 2)) * 1024 + k0 + (c & 3) * 8, sB + c * 8);
    }
    __syncthreads();
    bf16x8 af[4], bfv[4];
#pragma unroll
    for (int i = 0; i < 4; i++)
      af[i] = *(const bf16x8*)&sA[(wm * 64 + i * 16 + r) * 32 + qd * 8];
#pragma unroll
    for (int j = 0; j < 4; j++)
      bfv[j] = *(const bf16x8*)&sB[(wn * 64 + j * 16 + r) * 32 + qd * 8];
#pragma unroll
    for (int i = 0; i < 4; i++)
#pragma unroll
      for (int j = 0; j < 4; j++)
        acc[i][j] = __builtin_amdgcn_mfma_f32_16x16x32_bf16(af[i], bfv[j], acc[i][j], 0, 0, 0);
  }

  if (z < 2) {
    bf16* C = (z == 0) ? Cq : Ck;
    const float s = (z == 0) ? 0.1803368801f : 1.0f;   // 0.125*log2(e) folded into Q
#pragma unroll
    for (int i = 0; i < 4; i++)
#pragma unroll
      for (int j = 0; j < 4; j++)
#pragma unroll
        for (int rr = 0; rr < 4; rr++) {
          int row = m0 + wm * 64 + i * 16 + qd * 4 + rr;
          int col = n0 + wn * 64 + j * 16 + r;
          C[(size_t)row * 1024 + col] = (bf16)(acc[i][j][rr] * s);
        }
  } else {
    // V transpose epilogue: tile covers 2 heads (BN=128). sT[d_local][token], pad 136.
    __syncthreads();
#pragma unroll
    for (int i = 0; i < 4; i++)
#pragma unroll
      for (int j = 0; j < 4; j++) {
        int col = wn * 64 + j * 16 + r;
        int rowb = wm * 64 + i * 16 + qd * 4;
        bf16x4 v4;
#pragma unroll
        for (int rr = 0; rr < 4; rr++) v4[rr] = (bf16)acc[i][j][rr];
        *(bf16x4*)&smem[col * 136 + rowb] = v4;
      }
    __syncthreads();
    const int b = m0 >> 11, tok0 = m0 & 2047, h0 = n0 >> 6;
#pragma unroll
    for (int p = 0; p < 8; p++) {
      int c = p * 256 + tid;
      int dl = c >> 4, ch = c & 15;
      bf16x8 v = *(const bf16x8*)&smem[dl * 136 + ch * 8];
      int head = h0 + (dl >> 6), d = dl & 63;
      *(bf16x8*)(VT + ((size_t)((b * 16 + head) * 64 + d)) * 2048 + tok0 + ch * 8) = v;
    }
  }
}

// ---------------- output GEMM BM128/BN64 (512 blocks), FUSED split-K combine ----------------
// A = (OP_z0 + OP_z1) * (1/(LP.x+LP.y)) computed in registers during staging (T14
// async-split: next k-tile's 6 OP/LP loads issued after ds_write, counted vmcnt keeps
// them in flight across both raw barriers). B staged via global_load_lds as before.
__global__ __launch_bounds__(256) void gemm_nt_out(const bf16* __restrict__ OP,
                                                   const float* __restrict__ LP2,
                                                   const bf16* __restrict__ Bm,
                                                   void* __restrict__ Cout,
                                                   const int* __restrict__ flags) {
  __shared__ bf16 sA[128 * 32];
  __shared__ bf16 sB[64 * 32];
  const int tid = threadIdx.x;
  const int w = tid >> 6, lane = tid & 63, qd = lane >> 4, r = lane & 15;
  const int wm = w >> 1, wn = w & 1;
  const int m0 = blockIdx.x * 128, n0 = blockIdx.y * 64;

  // A-chunk geometry: chunk c -> row m0+(c>>2), k-col (c&3)*8 within the 32-wide k-tile
  const int c0 = tid, c1 = 256 + tid;
  const int row0 = m0 + (c0 >> 2), row1 = m0 + (c1 >> 2);
  const int kc0 = (c0 & 3) * 8, kc1 = (c1 & 3) * 8;

  bf16x8 oa0, ob0, oa1, ob1;   // OP z=0 / z=1 chunks
  float2 pl0, pl1;             // LP pairs (z0,z1) per row

#define LOADG(K0)                                                                     \
  {                                                                                   \
    int ka = (K0) + kc0, kb = (K0) + kc1;                                             \
    oa0 = *(const bf16x8*)(OP + (size_t)row0 * 1024 + ka);                            \
    ob0 = *(const bf16x8*)(OP + (size_t)4096 * 1024 + (size_t)row0 * 1024 + ka);      \
    pl0 = *(const float2*)(LP2 + ((size_t)row0 * 16 + (ka >> 6)) * 2);                \
    oa1 = *(const bf16x8*)(OP + (size_t)row1 * 1024 + kb);                            \
    ob1 = *(const bf16x8*)(OP + (size_t)4096 * 1024 + (size_t)row1 * 1024 + kb);      \
    pl1 = *(const float2*)(LP2 + ((size_t)row1 * 16 + (kb >> 6)) * 2);                \
  }

  f32x4 acc[4][2];
#pragma unroll
  for (int i = 0; i < 4; i++)
#pragma unroll
    for (int j = 0; j < 2; j++) acc[i][j] = (f32x4){0.f, 0.f, 0.f, 0.f};

  LOADG(0);   // prologue: 6 vmem in flight

  for (int k0 = 0; k0 < 1024; k0 += 32) {
    // B staging (1 gll16 per thread), issued while G(k) is landing
    gll16(Bm + (size_t)(n0 + (tid >> 2)) * 1024 + k0 + (tid & 3) * 8, sB + tid * 8);
    asm volatile("s_waitcnt vmcnt(1)" ::: "memory");   // G(k) done; B may fly
    __builtin_amdgcn_sched_barrier(0);
    // combine -> sA (identical arithmetic to the old combine kernel)
    {
      float i0 = 1.0f / (pl0.x + pl0.y);
      float i1 = 1.0f / (pl1.x + pl1.y);
      bf16x8 w0, w1;
#pragma unroll
      for (int e = 0; e < 8; e++) {
        w0[e] = (bf16)(((float)oa0[e] + (float)ob0[e]) * i0);
        w1[e] = (bf16)(((float)oa1[e] + (float)ob1[e]) * i1);
      }
      *(bf16x8*)(sA + c0 * 8) = w0;
      *(bf16x8*)(sA + c1 * 8) = w1;
    }
    if (k0 < 992) {
      LOADG(k0 + 32);                                   // 6 vmem for next tile
      asm volatile("s_waitcnt vmcnt(6)" ::: "memory");  // own B done; G(k+1) flies on
    } else {
      asm volatile("s_waitcnt vmcnt(0)" ::: "memory");
    }
    asm volatile("s_waitcnt lgkmcnt(0)" ::: "memory");  // sA ds_writes visible
    __builtin_amdgcn_sched_barrier(0);
    __builtin_amdgcn_s_barrier();

    bf16x8 af[4], bfv[2];
#pragma unroll
    for (int i = 0; i < 4; i++)
      af[i] = *(const bf16x8*)&sA[(wm * 64 + i * 16 + r) * 32 + qd * 8];
#pragma unroll
    for (int j = 0; j < 2; j++)
      bfv[j] = *(const bf16x8*)&sB[(wn * 32 + j * 16 + r) * 32 + qd * 8];
#pragma unroll
    for (int i = 0; i < 4; i++)
#pragma unroll
      for (int j = 0; j < 2; j++)
        acc[i][j] = __builtin_amdgcn_mfma_f32_16x16x32_bf16(af[i], bfv[j], acc[i][j], 0, 0, 0);
    __builtin_amdgcn_s_barrier();   // all reads done before next iter's ds_writes
  }
#undef LOADG

  const int f = flags[0];
#pragma unroll
  for (int i = 0; i < 4; i++)
#pragma unroll
    for (int j = 0; j < 2; j++)
#pragma unroll
      for (int rr = 0; rr < 4; rr++) {
        int row = m0 + wm * 64 + i * 16 + qd * 4 + rr;
        int col = n0 + wn * 32 + j * 16 + r;
        if (f) ((float*)Cout)[(size_t)row * 1024 + col] = acc[i][j][rr];
        else   ((bf16*)Cout)[(size_t)row * 1024 + col] = (bf16)acc[i][j][rr];
      }
}

// ---------------- flash attention: S^T trick, split-K, no-max softmax ----------------
// QK computed TRANSPOSED (A=K, B=Q): lane's 4 regs = 4 consecutive KEYS for one q-row
// -> P written as bf16x4 ds_write_b64 straight into A-operand layout. Mask = 1 nibble
// per (i,j) per lane. Q pre-scaled by 0.125*log2(e): exp(score)=2^S.
//
// v2: K/V double-buffered, raw s_barrier + counted vmcnt(6) (T3/T4), setprio (T5).
// v3: kt-loop unrolled x2 so buffer bases are compile-time; LP layout [row][h][z]
// so the fused output GEMM loads the pair with one 8B read.
__global__ __launch_bounds__(256) void attn_kernel(const bf16* __restrict__ Q,
                                                   const bf16* __restrict__ Kp,
                                                   const bf16* __restrict__ Vt,
                                                   const unsigned* __restrict__ bitsT,
                                                   bf16* __restrict__ OP,
                                                   float* __restrict__ LP) {
  __shared__ bf16 sK[2][64 * 64];    // [buf][key][d], chunk-swizzled
  __shared__ bf16 sVT[2][64 * 64];   // [buf][d][key], chunk-swizzled
  __shared__ bf16 sP[128 * 72];      // [q][key], wave-private rows
  const int tid = threadIdx.x;
  const int w = tid >> 6, lane = tid & 63, qd = lane >> 4, r = lane & 15;
  const int bh = blockIdx.y, b = bh >> 4, h = bh & 15;
  const int q0 = blockIdx.x * 128;
  const int z = blockIdx.z;

  bf16x8 qf[2][2];
#pragma unroll
  for (int i = 0; i < 2; i++)
#pragma unroll
    for (int ks = 0; ks < 2; ks++)
      qf[i][ks] = *(const bf16x8*)(Q + (size_t)(b * L_ + q0 + w * 32 + i * 16 + r) * D_ +
                                   h * HD_ + ks * 32 + qd * 8);

  bf16x8 ones;
#pragma unroll
  for (int e = 0; e < 8; e++) ones[e] = (bf16)1.0f;

  f32x4 o[2][4], lacc[2];
#pragma unroll
  for (int i = 0; i < 2; i++) {
#pragma unroll
    for (int dj = 0; dj < 4; dj++) o[i][dj] = (f32x4){0.f, 0.f, 0.f, 0.f};
    lacc[i] = (f32x4){0.f, 0.f, 0.f, 0.f};
  }

#define STAGE_KV(KT, KB, VB)                                                        \
  {                                                                                 \
    _Pragma("unroll")                                                               \
    for (int p = 0; p < 2; p++) {                                                   \
      int c = p * 256 + tid;                                                        \
      int row = c >> 3, kc = c & 7;                                                 \
      int kcg = kc ^ (row & 7);                                                     \
      gll16(Kp + (size_t)(b * L_ + (KT) * 64 + row) * D_ + h * HD_ + kcg * 8,       \
            (KB) + c * 8);                                                          \
    }                                                                               \
    _Pragma("unroll")                                                               \
    for (int p = 0; p < 2; p++) {                                                   \
      int c = p * 256 + tid;                                                        \
      int row = c >> 3, kc = c & 7;                                                 \
      int kcg = kc ^ (row & 7);                                                     \
      gll16(Vt + (size_t)(bh * 64 + row) * L_ + (KT) * 64 + kcg * 8, (VB) + c * 8); \
    }                                                                               \
  }

#define MLOAD(KT, M0, M1)                                                                       \
  {                                                                                             \
    M0 = *(const uint2*)(bitsT + ((size_t)(KT) * 4096 + b * 2048 + q0 + w * 32 + r) * 2);       \
    M1 = *(const uint2*)(bitsT + ((size_t)(KT) * 4096 + b * 2048 + q0 + w * 32 + 16 + r) * 2);  \
  }

  const int kt0 = z * 16;
  // prologue: stage tile 0 into buf 0, load its mask (6 vmem ops in flight)
  STAGE_KV(kt0, &sK[0][0], &sVT[0][0]);
  uint2 mc0, mc1, mn0, mn1;
  MLOAD(kt0, mc0, mc1);
  mn0 = mc0; mn1 = mc1;

#pragma unroll 2
  for (int it = 0; it < 16; ++it) {
    const int kt = kt0 + it;
    const bf16* kb = &sK[it & 1][0];
    const bf16* vb = &sVT[it & 1][0];

    if (it < 15) {
      // issue next tile's 6 vmem ops BEFORE waiting: they stay in flight across
      // the barrier and retire under this iteration's compute.
      STAGE_KV(kt + 1, &sK[(it + 1) & 1][0], &sVT[(it + 1) & 1][0]);
      MLOAD(kt + 1, mn0, mn1);
      asm volatile("s_waitcnt vmcnt(6)" ::: "memory");   // tile kt's 6 ops done
    } else {
      asm volatile("s_waitcnt vmcnt(0)" ::: "memory");
    }
    __builtin_amdgcn_sched_barrier(0);
    __builtin_amdgcn_s_barrier();     // all waves staged tile kt

    bf16x8 kf[4][2];
#pragma unroll
    for (int j = 0; j < 4; j++)
#pragma unroll
      for (int ks = 0; ks < 2; ks++) {
        int row = j * 16 + r;
        int phys = (ks * 4 + qd) ^ (row & 7);
        kf[j][ks] = *(const bf16x8*)&kb[row * 64 + phys * 8];
      }

#pragma unroll
    for (int i = 0; i < 2; i++) {
      f32x4 S[4];
      __builtin_amdgcn_s_setprio(1);
#pragma unroll
      for (int j = 0; j < 4; j++) {       // S^T: A=K (m=key), B=Q (n=q)
        S[j] = (f32x4){0.f, 0.f, 0.f, 0.f};
#pragma unroll
        for (int ks = 0; ks < 2; ks++)
          S[j] = __builtin_amdgcn_mfma_f32_16x16x32_bf16(kf[j][ks], qf[i][ks], S[j], 0, 0, 0);
      }
      __builtin_amdgcn_s_setprio(0);
      // lane holds: q = q0+w*32+i*16+r, keys kt*64 + j*16 + qd*4 + rr (rr contiguous!)
      const uint2 m64 = (i == 0) ? mc0 : mc1;
#pragma unroll
      for (int j = 0; j < 4; j++) {
        unsigned word = (j < 2) ? m64.x : m64.y;
        unsigned nib = (word >> ((j & 1) * 16 + qd * 4)) & 0xFu;
        bf16x4 pv;
#pragma unroll
        for (int rr = 0; rr < 4; rr++) {
          float e = fast_exp2(S[j][rr]);
          pv[rr] = (bf16)(((nib >> rr) & 1u) ? 0.f : e);
        }
        *(bf16x4*)&sP[(w * 32 + i * 16 + r) * 72 + j * 16 + qd * 4] = pv;
      }
    }
    asm volatile("s_waitcnt lgkmcnt(0)" ::: "memory");  // sP rows are wave-private

    bf16x8 vf[4][2];
#pragma unroll
    for (int dj = 0; dj < 4; dj++)
#pragma unroll
      for (int ks = 0; ks < 2; ks++) {
        int row = dj * 16 + r;
        int phys = (ks * 4 + qd) ^ (row & 7);
        vf[dj][ks] = *(const bf16x8*)&vb[row * 64 + phys * 8];
      }
    __builtin_amdgcn_s_setprio(1);
#pragma unroll
    for (int i = 0; i < 2; i++)
#pragma unroll
      for (int ks = 0; ks < 2; ks++) {
        bf16x8 pf = *(const bf16x8*)&sP[(w * 32 + i * 16 + r) * 72 + ks * 32 + qd * 8];
#pragma unroll
        for (int dj = 0; dj < 4; dj++)
          o[i][dj] = __builtin_amdgcn_mfma_f32_16x16x32_bf16(pf, vf[dj][ks], o[i][dj], 0, 0, 0);
        lacc[i] = __builtin_amdgcn_mfma_f32_16x16x32_bf16(pf, ones, lacc[i], 0, 0, 0);
      }
    __builtin_amdgcn_s_setprio(0);

    __builtin_amdgcn_s_barrier();     // all waves done reading buf[it&1]
    mc0 = mn0; mc1 = mn1;
  }
#undef STAGE_KV
#undef MLOAD

  // store partials (no divide here); LP layout [row][h][z] for the fused combine
#pragma unroll
  for (int i = 0; i < 2; i++) {
#pragma unroll
    for (int dj = 0; dj < 4; dj++)
#pragma unroll
      for (int rr = 0; rr < 4; rr++) {
        int rg = b * L_ + q0 + w * 32 + i * 16 + qd * 4 + rr;
        int col = h * HD_ + dj * 16 + r;
        OP[((size_t)z * 4096 + rg) * 1024 + col] = (bf16)o[i][dj][rr];
      }
    if (r == 0) {
#pragma unroll
      for (int rr = 0; rr < 4; rr++) {
        int rg = b * L_ + q0 + w * 32 + i * 16 + qd * 4 + rr;
        LP[((size_t)rg * 16 + h) * 2 + z] = lacc[i][rr];
      }
    }
  }
}

// ---------------- launch ----------------
extern "C" void kernel_launch(void* const* d_in, const int* in_sizes, int n_in,
                              void* d_out, int out_size, void* d_ws, size_t ws_size,
                              hipStream_t stream) {
  const void* xq = d_in[0];
  const void* xk = d_in[1];
  const void* xv = d_in[2];
  const void* Wq = d_in[3];
  const void* Wk = d_in[4];
  const void* Wv = d_in[5];
  const void* Wo = d_in[6];
  const void* mask = d_in[7];

  char* ws = (char*)d_ws;
  const size_t MB = 1048576;
  int*      FLAGS = (int*)(ws + 0);
  unsigned* BITS  = (unsigned*)(ws + 4096);          // 1 MB (transposed layout)
  bf16* cWo = (bf16*)(ws + 2 * MB);                  // lives until final GEMM
  bf16* cWq = (bf16*)(ws + 4 * MB);
  bf16* cWk = (bf16*)(ws + 6 * MB);
  bf16* cWv = (bf16*)(ws + 8 * MB);
  bf16* cxq = (bf16*)(ws + 10 * MB);
  bf16* cxk = (bf16*)(ws + 18 * MB);
  bf16* cxv = (bf16*)(ws + 26 * MB);
  bf16* Q   = (bf16*)(ws + 34 * MB);
  bf16* K   = (bf16*)(ws + 42 * MB);
  bf16* VT  = (bf16*)(ws + 50 * MB);
  // regions free after gemm_qkv are reused:
  bf16*  OP  = (bf16*)(ws + 4 * MB);    // 16 MB: [2][4096][1024] bf16
  float* LP  = (float*)(ws + 20 * MB);  // 512 KB: [4096][16][2] fp32

  detect_kernel<<<1, 256, 0, stream>>>((const unsigned short*)xq,
                                       (const unsigned char*)mask, FLAGS);
  canon_pack<<<9216, 256, 0, stream>>>(xq, xk, xv, Wq, Wk, Wv, Wo, mask,
                                       cxq, cxk, cxv, cWq, cWk, cWv, cWo,
                                       BITS, FLAGS);
  gemm_qkv<<<dim3(32, 8, 3), 256, 0, stream>>>(cxq, cWq, Q,
                                               cxk, cWk, K,
                                               cxv, cWv, VT);
  attn_kernel<<<dim3(16, 32, 2), 256, 0, stream>>>(Q, K, VT, BITS, OP, LP);
  gemm_nt_out<<<dim3(32, 16), 256, 0, stream>>>(OP, LP, cWo, d_out, FLAGS);
}

// Round 3
// 261.485 us; speedup vs baseline: 1.0719x; 1.0719x over previous
//
#include <hip/hip_runtime.h>
#include <hip/hip_bf16.h>

typedef __bf16 bf16;
typedef __attribute__((ext_vector_type(8))) __bf16 bf16x8;
typedef __attribute__((ext_vector_type(4))) __bf16 bf16x4;
typedef __attribute__((ext_vector_type(4))) float f32x4;

#define B_   2
#define L_   2048
#define D_   1024
#define H_   16
#define HD_  64

__device__ __forceinline__ float fast_exp2(float x) {
  float e; asm("v_exp_f32 %0, %1" : "=v"(e) : "v"(x)); return e;
}

// async global->LDS, 16B per lane. LDS dest = wave-uniform base + lane*16.
__device__ __forceinline__ void gll16(const bf16* g, bf16* l) {
  __builtin_amdgcn_global_load_lds((const __attribute__((address_space(1))) void*)g,
                                   (__attribute__((address_space(3))) void*)l,
                                   16, 0, 0);
}

// ---------------- dtype + mask-layout detection ----------------
__global__ void detect_kernel(const unsigned short* __restrict__ q_u,
                              const unsigned char* __restrict__ m_u,
                              int* __restrict__ flags) {
  __shared__ int cnt, odd;
  if (threadIdx.x == 0) { cnt = 0; odd = 0; }
  __syncthreads();
  int c = 0, o = 0;
  for (int i = 0; i < 8; i++) {
    int idx = threadIdx.x * 8 + i;
    unsigned e = (q_u[idx] >> 7) & 0xFF;
    if (e >= 0x8F || (e > 0 && e <= 0x6F)) c++;   // wild exponent
    if ((idx & 3) && m_u[idx]) o = 1;             // nonzero odd byte -> int8 mask
  }
  atomicAdd(&cnt, c);
  if (o) atomicOr(&odd, 1);
  __syncthreads();
  if (threadIdx.x == 0) { flags[0] = (cnt > 128) ? 1 : 0; flags[1] = odd; }
}

// ---------------- canonicalize (7 tensors) + mask bit-pack, ONE launch ----------------
__device__ __forceinline__ void canon_body(const void* src, bf16* dst, int i, int f) {
  if (f) {
    const float4* s = (const float4*)src;
    float4 a = s[i / 4], b2 = s[i / 4 + 1];
    bf16x8 o;
    o[0] = (bf16)a.x;  o[1] = (bf16)a.y;  o[2] = (bf16)a.z;  o[3] = (bf16)a.w;
    o[4] = (bf16)b2.x; o[5] = (bf16)b2.y; o[6] = (bf16)b2.z; o[7] = (bf16)b2.w;
    *(bf16x8*)(dst + i) = o;
  } else {
    *(bf16x8*)(dst + i) = ((const bf16x8*)src)[i / 8];
  }
}

__global__ __launch_bounds__(256) void canon_pack(
    const void* xq, const void* xk, const void* xv,
    const void* Wq, const void* Wk, const void* Wv, const void* Wo,
    const void* mp,
    bf16* cxq, bf16* cxk, bf16* cxv,
    bf16* cWq, bf16* cWk, bf16* cWv, bf16* cWo,
    unsigned* __restrict__ bitsT,
    const int* __restrict__ flags) {
  int t = blockIdx.x;
  if (t >= 8192) {
    // ---- mask pack: bitsT[(kt*4096+row)*2+half], transposed layout ----
    int wid = (t - 8192) * 256 + threadIdx.x;   // one 32-bit word per thread
    unsigned v = 0;
    if (flags[1]) {                              // int8 layout
      const uchar4* p = (const uchar4*)mp;
#pragma unroll
      for (int c = 0; c < 8; c++) {
        uchar4 u = p[wid * 8 + c];
        v |= (u.x ? 1u : 0u) << (c * 4 + 0);
        v |= (u.y ? 1u : 0u) << (c * 4 + 1);
        v |= (u.z ? 1u : 0u) << (c * 4 + 2);
        v |= (u.w ? 1u : 0u) << (c * 4 + 3);
      }
    } else {                                     // int32 layout
      const int4* p = (const int4*)mp;
#pragma unroll
      for (int c = 0; c < 8; c++) {
        int4 u = p[wid * 8 + c];
        v |= (u.x ? 1u : 0u) << (c * 4 + 0);
        v |= (u.y ? 1u : 0u) << (c * 4 + 1);
        v |= (u.z ? 1u : 0u) << (c * 4 + 2);
        v |= (u.w ? 1u : 0u) << (c * 4 + 3);
      }
    }
    int row = wid >> 6, word = wid & 63;
    int kt = word >> 1, half = word & 1;
    bitsT[((size_t)kt * 4096 + row) * 2 + half] = v;
    return;
  }
  const int f = flags[0];
  const void* src; bf16* dst; int base;
  if (t < 2048)      { src = xq; dst = cxq; base = t * 2048; }
  else if (t < 4096) { src = xk; dst = cxk; base = (t - 2048) * 2048; }
  else if (t < 6144) { src = xv; dst = cxv; base = (t - 4096) * 2048; }
  else {
    int w = t - 6144, wi = w >> 9;
    base = (w & 511) * 2048;
    if (wi == 0)      { src = Wq; dst = cWq; }
    else if (wi == 1) { src = Wk; dst = cWk; }
    else if (wi == 2) { src = Wv; dst = cWv; }
    else              { src = Wo; dst = cWo; }
  }
  canon_body(src, dst, base + threadIdx.x * 8, f);
}

// ---------------- fused QKV NT GEMM, 128x128 tile ----------------
// z==0: Q scaled by 0.125*log2(e). z==1: K. z==2: V -> VT transposed per head.
__global__ __launch_bounds__(256) void gemm_qkv(
    const bf16* __restrict__ Aq, const bf16* __restrict__ Bq, bf16* __restrict__ Cq,
    const bf16* __restrict__ Ak, const bf16* __restrict__ Bk, bf16* __restrict__ Ck,
    const bf16* __restrict__ Av, const bf16* __restrict__ Bv, bf16* __restrict__ VT) {
  __shared__ bf16 smem[128 * 136];
  bf16* sA = smem;
  bf16* sB = smem + 4096;
  const int z = blockIdx.z;
  const bf16* A  = (z == 0) ? Aq : (z == 1) ? Ak : Av;
  const bf16* Bm = (z == 0) ? Bq : (z == 1) ? Bk : Bv;

  const int tid = threadIdx.x;
  const int w = tid >> 6, lane = tid & 63, qd = lane >> 4, r = lane & 15;
  const int wm = w >> 1, wn = w & 1;
  const int m0 = blockIdx.x * 128, n0 = blockIdx.y * 128;

  f32x4 acc[4][4];
#pragma unroll
  for (int i = 0; i < 4; i++)
#pragma unroll
    for (int j = 0; j < 4; j++) acc[i][j] = (f32x4){0.f, 0.f, 0.f, 0.f};

  for (int k0 = 0; k0 < 1024; k0 += 32) {
    __syncthreads();
#pragma unroll
    for (int p = 0; p < 2; p++) {
      int c = p * 256 + tid;
      gll16(A + (size_t)(m0 + (c >> 2)) * 1024 + k0 + (c & 3) * 8, sA + c * 8);
    }
#pragma unroll
    for (int p = 0; p < 2; p++) {
      int c = p * 256 + tid;
      gll16(Bm + (size_t)(n0 + (c >> 2)) * 1024 + k0 + (c & 3) * 8, sB + c * 8);
    }
    __syncthreads();
    bf16x8 af[4], bfv[4];
#pragma unroll
    for (int i = 0; i < 4; i++)
      af[i] = *(const bf16x8*)&sA[(wm * 64 + i * 16 + r) * 32 + qd * 8];
#pragma unroll
    for (int j = 0; j < 4; j++)
      bfv[j] = *(const bf16x8*)&sB[(wn * 64 + j * 16 + r) * 32 + qd * 8];
#pragma unroll
    for (int i = 0; i < 4; i++)
#pragma unroll
      for (int j = 0; j < 4; j++)
        acc[i][j] = __builtin_amdgcn_mfma_f32_16x16x32_bf16(af[i], bfv[j], acc[i][j], 0, 0, 0);
  }

  if (z < 2) {
    bf16* C = (z == 0) ? Cq : Ck;
    const float s = (z == 0) ? 0.1803368801f : 1.0f;   // 0.125*log2(e) folded into Q
#pragma unroll
    for (int i = 0; i < 4; i++)
#pragma unroll
      for (int j = 0; j < 4; j++)
#pragma unroll
        for (int rr = 0; rr < 4; rr++) {
          int row = m0 + wm * 64 + i * 16 + qd * 4 + rr;
          int col = n0 + wn * 64 + j * 16 + r;
          C[(size_t)row * 1024 + col] = (bf16)(acc[i][j][rr] * s);
        }
  } else {
    // V transpose epilogue: tile covers 2 heads (BN=128). sT[d_local][token], pad 136.
    __syncthreads();
#pragma unroll
    for (int i = 0; i < 4; i++)
#pragma unroll
      for (int j = 0; j < 4; j++) {
        int col = wn * 64 + j * 16 + r;
        int rowb = wm * 64 + i * 16 + qd * 4;
        bf16x4 v4;
#pragma unroll
        for (int rr = 0; rr < 4; rr++) v4[rr] = (bf16)acc[i][j][rr];
        *(bf16x4*)&smem[col * 136 + rowb] = v4;
      }
    __syncthreads();
    const int b = m0 >> 11, tok0 = m0 & 2047, h0 = n0 >> 6;
#pragma unroll
    for (int p = 0; p < 8; p++) {
      int c = p * 256 + tid;
      int dl = c >> 4, ch = c & 15;
      bf16x8 v = *(const bf16x8*)&smem[dl * 136 + ch * 8];
      int head = h0 + (dl >> 6), d = dl & 63;
      *(bf16x8*)(VT + ((size_t)((b * 16 + head) * 64 + d)) * 2048 + tok0 + ch * 8) = v;
    }
  }
}

// ---------------- output GEMM BM128/BN64 (512 blocks): flagged store ----------------
__global__ __launch_bounds__(256) void gemm_nt_out(const bf16* __restrict__ A,
                                                   const bf16* __restrict__ Bm,
                                                   void* __restrict__ Cout,
                                                   const int* __restrict__ flags) {
  __shared__ bf16 sA[128 * 32];
  __shared__ bf16 sB[64 * 32];
  const int tid = threadIdx.x;
  const int w = tid >> 6, lane = tid & 63, qd = lane >> 4, r = lane & 15;
  const int wm = w >> 1, wn = w & 1;
  const int m0 = blockIdx.x * 128, n0 = blockIdx.y * 64;

  f32x4 acc[4][2];
#pragma unroll
  for (int i = 0; i < 4; i++)
#pragma unroll
    for (int j = 0; j < 2; j++) acc[i][j] = (f32x4){0.f, 0.f, 0.f, 0.f};

  for (int k0 = 0; k0 < 1024; k0 += 32) {
    __syncthreads();
    {
      int c0 = tid;
      gll16(A + (size_t)(m0 + (c0 >> 2)) * 1024 + k0 + (c0 & 3) * 8, sA + c0 * 8);
      int c1 = 256 + tid;
      gll16(A + (size_t)(m0 + (c1 >> 2)) * 1024 + k0 + (c1 & 3) * 8, sA + c1 * 8);
      int cb = tid;
      gll16(Bm + (size_t)(n0 + (cb >> 2)) * 1024 + k0 + (cb & 3) * 8, sB + cb * 8);
    }
    __syncthreads();
    bf16x8 af[4], bfv[2];
#pragma unroll
    for (int i = 0; i < 4; i++)
      af[i] = *(const bf16x8*)&sA[(wm * 64 + i * 16 + r) * 32 + qd * 8];
#pragma unroll
    for (int j = 0; j < 2; j++)
      bfv[j] = *(const bf16x8*)&sB[(wn * 32 + j * 16 + r) * 32 + qd * 8];
#pragma unroll
    for (int i = 0; i < 4; i++)
#pragma unroll
      for (int j = 0; j < 2; j++)
        acc[i][j] = __builtin_amdgcn_mfma_f32_16x16x32_bf16(af[i], bfv[j], acc[i][j], 0, 0, 0);
  }
  const int f = flags[0];
#pragma unroll
  for (int i = 0; i < 4; i++)
#pragma unroll
    for (int j = 0; j < 2; j++)
#pragma unroll
      for (int rr = 0; rr < 4; rr++) {
        int row = m0 + wm * 64 + i * 16 + qd * 4 + rr;
        int col = n0 + wn * 32 + j * 16 + r;
        if (f) ((float*)Cout)[(size_t)row * 1024 + col] = acc[i][j][rr];
        else   ((bf16*)Cout)[(size_t)row * 1024 + col] = (bf16)acc[i][j][rr];
      }
}

// ---------------- flash attention: S^T trick, NO split-K, no-max softmax ----------------
// QK computed TRANSPOSED (A=K, B=Q): lane's 4 regs = 4 consecutive KEYS for one q-row
// -> P written as bf16x4 ds_write_b64 straight into A-operand layout. Mask = 1 nibble
// per (i,j) per lane. Q pre-scaled by 0.125*log2(e): exp(score)=2^S.
//
// v4: split-K removed (each block walks all 32 KV tiles, divides by l in-register,
// writes final CTX -> combine kernel + OP/LP traffic gone; 512 blocks = exactly
// 2/CU resident, zero dispatch tail). XCD-group swizzle: all 16 q-blocks of one
// (b,h) land on one XCD so its 512 KB of K/V stays in that XCD's L2 (T1).
// K/V double-buffered, raw s_barrier + counted vmcnt(6) (T3/T4), setprio (T5).
__global__ __launch_bounds__(256) void attn_kernel(const bf16* __restrict__ Q,
                                                   const bf16* __restrict__ Kp,
                                                   const bf16* __restrict__ Vt,
                                                   const unsigned* __restrict__ bitsT,
                                                   bf16* __restrict__ CTX) {
  __shared__ bf16 sK[2][64 * 64];    // [buf][key][d], chunk-swizzled
  __shared__ bf16 sVT[2][64 * 64];   // [buf][d][key], chunk-swizzled
  __shared__ bf16 sP[128 * 72];      // [q][key], wave-private rows
  const int tid = threadIdx.x;
  const int w = tid >> 6, lane = tid & 63, qd = lane >> 4, r = lane & 15;
  // XCD-group swizzle: wgid%8 = XCD (round-robin dispatch). Group g=(b,h) of 16
  // q-blocks must share one XCD: g = (wgid>>7)*8 + (wgid&7), qb = (wgid>>3)&15.
  const int wgid = blockIdx.x;
  const int bh = ((wgid >> 7) << 3) + (wgid & 7);   // 0..31
  const int b = bh >> 4, h = bh & 15;
  const int q0 = ((wgid >> 3) & 15) * 128;

  bf16x8 qf[2][2];
#pragma unroll
  for (int i = 0; i < 2; i++)
#pragma unroll
    for (int ks = 0; ks < 2; ks++)
      qf[i][ks] = *(const bf16x8*)(Q + (size_t)(b * L_ + q0 + w * 32 + i * 16 + r) * D_ +
                                   h * HD_ + ks * 32 + qd * 8);

  bf16x8 ones;
#pragma unroll
  for (int e = 0; e < 8; e++) ones[e] = (bf16)1.0f;

  f32x4 o[2][4], lacc[2];
#pragma unroll
  for (int i = 0; i < 2; i++) {
#pragma unroll
    for (int dj = 0; dj < 4; dj++) o[i][dj] = (f32x4){0.f, 0.f, 0.f, 0.f};
    lacc[i] = (f32x4){0.f, 0.f, 0.f, 0.f};
  }

#define STAGE_KV(KT, KB, VB)                                                        \
  {                                                                                 \
    _Pragma("unroll")                                                               \
    for (int p = 0; p < 2; p++) {                                                   \
      int c = p * 256 + tid;                                                        \
      int row = c >> 3, kc = c & 7;                                                 \
      int kcg = kc ^ (row & 7);                                                     \
      gll16(Kp + (size_t)(b * L_ + (KT) * 64 + row) * D_ + h * HD_ + kcg * 8,       \
            (KB) + c * 8);                                                          \
    }                                                                               \
    _Pragma("unroll")                                                               \
    for (int p = 0; p < 2; p++) {                                                   \
      int c = p * 256 + tid;                                                        \
      int row = c >> 3, kc = c & 7;                                                 \
      int kcg = kc ^ (row & 7);                                                     \
      gll16(Vt + (size_t)(bh * 64 + row) * L_ + (KT) * 64 + kcg * 8, (VB) + c * 8); \
    }                                                                               \
  }

#define MLOAD(KT, M0, M1)                                                                       \
  {                                                                                             \
    M0 = *(const uint2*)(bitsT + ((size_t)(KT) * 4096 + b * 2048 + q0 + w * 32 + r) * 2);       \
    M1 = *(const uint2*)(bitsT + ((size_t)(KT) * 4096 + b * 2048 + q0 + w * 32 + 16 + r) * 2);  \
  }

  // prologue: stage tile 0 into buf 0, load its mask (6 vmem ops in flight)
  STAGE_KV(0, &sK[0][0], &sVT[0][0]);
  uint2 mc0, mc1, mn0, mn1;
  MLOAD(0, mc0, mc1);
  mn0 = mc0; mn1 = mc1;

#pragma unroll 2
  for (int it = 0; it < 32; ++it) {
    const bf16* kb = &sK[it & 1][0];
    const bf16* vb = &sVT[it & 1][0];

    if (it < 31) {
      // issue next tile's 6 vmem ops BEFORE waiting: they stay in flight across
      // the barrier and retire under this iteration's compute.
      STAGE_KV(it + 1, &sK[(it + 1) & 1][0], &sVT[(it + 1) & 1][0]);
      MLOAD(it + 1, mn0, mn1);
      asm volatile("s_waitcnt vmcnt(6)" ::: "memory");   // tile it's 6 ops done
    } else {
      asm volatile("s_waitcnt vmcnt(0)" ::: "memory");
    }
    __builtin_amdgcn_sched_barrier(0);
    __builtin_amdgcn_s_barrier();     // all waves staged tile it

    bf16x8 kf[4][2];
#pragma unroll
    for (int j = 0; j < 4; j++)
#pragma unroll
      for (int ks = 0; ks < 2; ks++) {
        int row = j * 16 + r;
        int phys = (ks * 4 + qd) ^ (row & 7);
        kf[j][ks] = *(const bf16x8*)&kb[row * 64 + phys * 8];
      }

#pragma unroll
    for (int i = 0; i < 2; i++) {
      f32x4 S[4];
      __builtin_amdgcn_s_setprio(1);
#pragma unroll
      for (int j = 0; j < 4; j++) {       // S^T: A=K (m=key), B=Q (n=q)
        S[j] = (f32x4){0.f, 0.f, 0.f, 0.f};
#pragma unroll
        for (int ks = 0; ks < 2; ks++)
          S[j] = __builtin_amdgcn_mfma_f32_16x16x32_bf16(kf[j][ks], qf[i][ks], S[j], 0, 0, 0);
      }
      __builtin_amdgcn_s_setprio(0);
      // lane holds: q = q0+w*32+i*16+r, keys it*64 + j*16 + qd*4 + rr (rr contiguous!)
      const uint2 m64 = (i == 0) ? mc0 : mc1;
#pragma unroll
      for (int j = 0; j < 4; j++) {
        unsigned word = (j < 2) ? m64.x : m64.y;
        unsigned nib = (word >> ((j & 1) * 16 + qd * 4)) & 0xFu;
        bf16x4 pv;
#pragma unroll
        for (int rr = 0; rr < 4; rr++) {
          float e = fast_exp2(S[j][rr]);
          pv[rr] = (bf16)(((nib >> rr) & 1u) ? 0.f : e);
        }
        *(bf16x4*)&sP[(w * 32 + i * 16 + r) * 72 + j * 16 + qd * 4] = pv;
      }
    }
    asm volatile("s_waitcnt lgkmcnt(0)" ::: "memory");  // sP rows are wave-private

    bf16x8 vf[4][2];
#pragma unroll
    for (int dj = 0; dj < 4; dj++)
#pragma unroll
      for (int ks = 0; ks < 2; ks++) {
        int row = dj * 16 + r;
        int phys = (ks * 4 + qd) ^ (row & 7);
        vf[dj][ks] = *(const bf16x8*)&vb[row * 64 + phys * 8];
      }
    __builtin_amdgcn_s_setprio(1);
#pragma unroll
    for (int i = 0; i < 2; i++)
#pragma unroll
      for (int ks = 0; ks < 2; ks++) {
        bf16x8 pf = *(const bf16x8*)&sP[(w * 32 + i * 16 + r) * 72 + ks * 32 + qd * 8];
#pragma unroll
        for (int dj = 0; dj < 4; dj++)
          o[i][dj] = __builtin_amdgcn_mfma_f32_16x16x32_bf16(pf, vf[dj][ks], o[i][dj], 0, 0, 0);
        lacc[i] = __builtin_amdgcn_mfma_f32_16x16x32_bf16(pf, ones, lacc[i], 0, 0, 0);
      }
    __builtin_amdgcn_s_setprio(0);

    __builtin_amdgcn_s_barrier();     // all waves done reading buf[it&1]
    mc0 = mn0; mc1 = mn1;
  }
#undef STAGE_KV
#undef MLOAD

  // epilogue: divide by row-sum in-register, write final CTX (bf16)
#pragma unroll
  for (int i = 0; i < 2; i++) {
    float inv[4];
#pragma unroll
    for (int rr = 0; rr < 4; rr++) inv[rr] = 1.0f / lacc[i][rr];
#pragma unroll
    for (int dj = 0; dj < 4; dj++)
#pragma unroll
      for (int rr = 0; rr < 4; rr++) {
        int rg = b * L_ + q0 + w * 32 + i * 16 + qd * 4 + rr;
        int col = h * HD_ + dj * 16 + r;
        CTX[(size_t)rg * 1024 + col] = (bf16)(o[i][dj][rr] * inv[rr]);
      }
  }
}

// ---------------- launch ----------------
extern "C" void kernel_launch(void* const* d_in, const int* in_sizes, int n_in,
                              void* d_out, int out_size, void* d_ws, size_t ws_size,
                              hipStream_t stream) {
  const void* xq = d_in[0];
  const void* xk = d_in[1];
  const void* xv = d_in[2];
  const void* Wq = d_in[3];
  const void* Wk = d_in[4];
  const void* Wv = d_in[5];
  const void* Wo = d_in[6];
  const void* mask = d_in[7];

  char* ws = (char*)d_ws;
  const size_t MB = 1048576;
  int*      FLAGS = (int*)(ws + 0);
  unsigned* BITS  = (unsigned*)(ws + 4096);          // 1 MB (transposed layout)
  bf16* cWo = (bf16*)(ws + 2 * MB);                  // lives until final GEMM
  bf16* cWq = (bf16*)(ws + 4 * MB);
  bf16* cWk = (bf16*)(ws + 6 * MB);
  bf16* cWv = (bf16*)(ws + 8 * MB);
  bf16* cxq = (bf16*)(ws + 10 * MB);
  bf16* cxk = (bf16*)(ws + 18 * MB);
  bf16* cxv = (bf16*)(ws + 26 * MB);
  bf16* Q   = (bf16*)(ws + 34 * MB);
  bf16* K   = (bf16*)(ws + 42 * MB);
  bf16* VT  = (bf16*)(ws + 50 * MB);
  // cxv region is free after gemm_qkv -> CTX reuses it:
  bf16* CTX = (bf16*)(ws + 26 * MB);    // 8 MB: [4096][1024] bf16

  detect_kernel<<<1, 256, 0, stream>>>((const unsigned short*)xq,
                                       (const unsigned char*)mask, FLAGS);
  canon_pack<<<9216, 256, 0, stream>>>(xq, xk, xv, Wq, Wk, Wv, Wo, mask,
                                       cxq, cxk, cxv, cWq, cWk, cWv, cWo,
                                       BITS, FLAGS);
  gemm_qkv<<<dim3(32, 8, 3), 256, 0, stream>>>(cxq, cWq, Q,
                                               cxk, cWk, K,
                                               cxv, cWv, VT);
  attn_kernel<<<512, 256, 0, stream>>>(Q, K, VT, BITS, CTX);
  gemm_nt_out<<<dim3(32, 16), 256, 0, stream>>>(CTX, cWo, d_out, FLAGS);
}

// Round 4
// 253.292 us; speedup vs baseline: 1.1065x; 1.0323x over previous
//
#include <hip/hip_runtime.h>
#include <hip/hip_bf16.h>

typedef __bf16 bf16;
typedef __attribute__((ext_vector_type(8))) __bf16 bf16x8;
typedef __attribute__((ext_vector_type(4))) __bf16 bf16x4;
typedef __attribute__((ext_vector_type(4))) float f32x4;

#define B_   2
#define L_   2048
#define D_   1024
#define H_   16
#define HD_  64

__device__ __forceinline__ float fast_exp2(float x) {
  float e; asm("v_exp_f32 %0, %1" : "=v"(e) : "v"(x)); return e;
}

// async global->LDS, 16B per lane. LDS dest = wave-uniform base + lane*16.
__device__ __forceinline__ void gll16(const bf16* g, bf16* l) {
  __builtin_amdgcn_global_load_lds((const __attribute__((address_space(1))) void*)g,
                                   (__attribute__((address_space(3))) void*)l,
                                   16, 0, 0);
}

// ---------------- dtype + mask-layout detection ----------------
__global__ void detect_kernel(const unsigned short* __restrict__ q_u,
                              const unsigned char* __restrict__ m_u,
                              int* __restrict__ flags) {
  __shared__ int cnt, odd;
  if (threadIdx.x == 0) { cnt = 0; odd = 0; }
  __syncthreads();
  int c = 0, o = 0;
  for (int i = 0; i < 8; i++) {
    int idx = threadIdx.x * 8 + i;
    unsigned e = (q_u[idx] >> 7) & 0xFF;
    if (e >= 0x8F || (e > 0 && e <= 0x6F)) c++;   // wild exponent
    if ((idx & 3) && m_u[idx]) o = 1;             // nonzero odd byte -> int8 mask
  }
  atomicAdd(&cnt, c);
  if (o) atomicOr(&odd, 1);
  __syncthreads();
  if (threadIdx.x == 0) { flags[0] = (cnt > 128) ? 1 : 0; flags[1] = odd; }
}

// ---------------- canonicalize (7 tensors) + mask bit-pack, ONE launch ----------------
__device__ __forceinline__ void canon_body(const void* src, bf16* dst, int i, int f) {
  if (f) {
    const float4* s = (const float4*)src;
    float4 a = s[i / 4], b2 = s[i / 4 + 1];
    bf16x8 o;
    o[0] = (bf16)a.x;  o[1] = (bf16)a.y;  o[2] = (bf16)a.z;  o[3] = (bf16)a.w;
    o[4] = (bf16)b2.x; o[5] = (bf16)b2.y; o[6] = (bf16)b2.z; o[7] = (bf16)b2.w;
    *(bf16x8*)(dst + i) = o;
  } else {
    *(bf16x8*)(dst + i) = ((const bf16x8*)src)[i / 8];
  }
}

__global__ __launch_bounds__(256) void canon_pack(
    const void* xq, const void* xk, const void* xv,
    const void* Wq, const void* Wk, const void* Wv, const void* Wo,
    const void* mp,
    bf16* cxq, bf16* cxk, bf16* cxv,
    bf16* cWq, bf16* cWk, bf16* cWv, bf16* cWo,
    unsigned* __restrict__ bitsT,
    const int* __restrict__ flags) {
  int t = blockIdx.x;
  if (t >= 8192) {
    // ---- mask pack: bitsT[(kt*4096+row)*2+half], transposed layout ----
    int wid = (t - 8192) * 256 + threadIdx.x;   // one 32-bit word per thread
    unsigned v = 0;
    if (flags[1]) {                              // int8 layout
      const uchar4* p = (const uchar4*)mp;
#pragma unroll
      for (int c = 0; c < 8; c++) {
        uchar4 u = p[wid * 8 + c];
        v |= (u.x ? 1u : 0u) << (c * 4 + 0);
        v |= (u.y ? 1u : 0u) << (c * 4 + 1);
        v |= (u.z ? 1u : 0u) << (c * 4 + 2);
        v |= (u.w ? 1u : 0u) << (c * 4 + 3);
      }
    } else {                                     // int32 layout
      const int4* p = (const int4*)mp;
#pragma unroll
      for (int c = 0; c < 8; c++) {
        int4 u = p[wid * 8 + c];
        v |= (u.x ? 1u : 0u) << (c * 4 + 0);
        v |= (u.y ? 1u : 0u) << (c * 4 + 1);
        v |= (u.z ? 1u : 0u) << (c * 4 + 2);
        v |= (u.w ? 1u : 0u) << (c * 4 + 3);
      }
    }
    int row = wid >> 6, word = wid & 63;
    int kt = word >> 1, half = word & 1;
    bitsT[((size_t)kt * 4096 + row) * 2 + half] = v;
    return;
  }
  const int f = flags[0];
  const void* src; bf16* dst; int base;
  if (t < 2048)      { src = xq; dst = cxq; base = t * 2048; }
  else if (t < 4096) { src = xk; dst = cxk; base = (t - 2048) * 2048; }
  else if (t < 6144) { src = xv; dst = cxv; base = (t - 4096) * 2048; }
  else {
    int w = t - 6144, wi = w >> 9;
    base = (w & 511) * 2048;
    if (wi == 0)      { src = Wq; dst = cWq; }
    else if (wi == 1) { src = Wk; dst = cWk; }
    else if (wi == 2) { src = Wv; dst = cWv; }
    else              { src = Wo; dst = cWo; }
  }
  canon_body(src, dst, base + threadIdx.x * 8, f);
}

// ---------------- fused QKV NT GEMM, 128x128 tile ----------------
// z==0: Q scaled by 0.125*log2(e). z==1: K. z==2: V -> VT transposed per head.
__global__ __launch_bounds__(256) void gemm_qkv(
    const bf16* __restrict__ Aq, const bf16* __restrict__ Bq, bf16* __restrict__ Cq,
    const bf16* __restrict__ Ak, const bf16* __restrict__ Bk, bf16* __restrict__ Ck,
    const bf16* __restrict__ Av, const bf16* __restrict__ Bv, bf16* __restrict__ VT) {
  __shared__ bf16 smem[128 * 136];
  bf16* sA = smem;
  bf16* sB = smem + 4096;
  const int z = blockIdx.z;
  const bf16* A  = (z == 0) ? Aq : (z == 1) ? Ak : Av;
  const bf16* Bm = (z == 0) ? Bq : (z == 1) ? Bk : Bv;

  const int tid = threadIdx.x;
  const int w = tid >> 6, lane = tid & 63, qd = lane >> 4, r = lane & 15;
  const int wm = w >> 1, wn = w & 1;
  const int m0 = blockIdx.x * 128, n0 = blockIdx.y * 128;

  f32x4 acc[4][4];
#pragma unroll
  for (int i = 0; i < 4; i++)
#pragma unroll
    for (int j = 0; j < 4; j++) acc[i][j] = (f32x4){0.f, 0.f, 0.f, 0.f};

  for (int k0 = 0; k0 < 1024; k0 += 32) {
    __syncthreads();
#pragma unroll
    for (int p = 0; p < 2; p++) {
      int c = p * 256 + tid;
      gll16(A + (size_t)(m0 + (c >> 2)) * 1024 + k0 + (c & 3) * 8, sA + c * 8);
    }
#pragma unroll
    for (int p = 0; p < 2; p++) {
      int c = p * 256 + tid;
      gll16(Bm + (size_t)(n0 + (c >> 2)) * 1024 + k0 + (c & 3) * 8, sB + c * 8);
    }
    __syncthreads();
    bf16x8 af[4], bfv[4];
#pragma unroll
    for (int i = 0; i < 4; i++)
      af[i] = *(const bf16x8*)&sA[(wm * 64 + i * 16 + r) * 32 + qd * 8];
#pragma unroll
    for (int j = 0; j < 4; j++)
      bfv[j] = *(const bf16x8*)&sB[(wn * 64 + j * 16 + r) * 32 + qd * 8];
#pragma unroll
    for (int i = 0; i < 4; i++)
#pragma unroll
      for (int j = 0; j < 4; j++)
        acc[i][j] = __builtin_amdgcn_mfma_f32_16x16x32_bf16(af[i], bfv[j], acc[i][j], 0, 0, 0);
  }

  if (z < 2) {
    bf16* C = (z == 0) ? Cq : Ck;
    const float s = (z == 0) ? 0.1803368801f : 1.0f;   // 0.125*log2(e) folded into Q
#pragma unroll
    for (int i = 0; i < 4; i++)
#pragma unroll
      for (int j = 0; j < 4; j++)
#pragma unroll
        for (int rr = 0; rr < 4; rr++) {
          int row = m0 + wm * 64 + i * 16 + qd * 4 + rr;
          int col = n0 + wn * 64 + j * 16 + r;
          C[(size_t)row * 1024 + col] = (bf16)(acc[i][j][rr] * s);
        }
  } else {
    // V transpose epilogue: tile covers 2 heads (BN=128). sT[d_local][token], pad 136.
    __syncthreads();
#pragma unroll
    for (int i = 0; i < 4; i++)
#pragma unroll
      for (int j = 0; j < 4; j++) {
        int col = wn * 64 + j * 16 + r;
        int rowb = wm * 64 + i * 16 + qd * 4;
        bf16x4 v4;
#pragma unroll
        for (int rr = 0; rr < 4; rr++) v4[rr] = (bf16)acc[i][j][rr];
        *(bf16x4*)&smem[col * 136 + rowb] = v4;
      }
    __syncthreads();
    const int b = m0 >> 11, tok0 = m0 & 2047, h0 = n0 >> 6;
#pragma unroll
    for (int p = 0; p < 8; p++) {
      int c = p * 256 + tid;
      int dl = c >> 4, ch = c & 15;
      bf16x8 v = *(const bf16x8*)&smem[dl * 136 + ch * 8];
      int head = h0 + (dl >> 6), d = dl & 63;
      *(bf16x8*)(VT + ((size_t)((b * 16 + head) * 64 + d)) * 2048 + tok0 + ch * 8) = v;
    }
  }
}

// ---------------- output GEMM BM128/BN64 (512 blocks): flagged store ----------------
__global__ __launch_bounds__(256) void gemm_nt_out(const bf16* __restrict__ A,
                                                   const bf16* __restrict__ Bm,
                                                   void* __restrict__ Cout,
                                                   const int* __restrict__ flags) {
  __shared__ bf16 sA[128 * 32];
  __shared__ bf16 sB[64 * 32];
  const int tid = threadIdx.x;
  const int w = tid >> 6, lane = tid & 63, qd = lane >> 4, r = lane & 15;
  const int wm = w >> 1, wn = w & 1;
  const int m0 = blockIdx.x * 128, n0 = blockIdx.y * 64;

  f32x4 acc[4][2];
#pragma unroll
  for (int i = 0; i < 4; i++)
#pragma unroll
    for (int j = 0; j < 2; j++) acc[i][j] = (f32x4){0.f, 0.f, 0.f, 0.f};

  for (int k0 = 0; k0 < 1024; k0 += 32) {
    __syncthreads();
    {
      int c0 = tid;
      gll16(A + (size_t)(m0 + (c0 >> 2)) * 1024 + k0 + (c0 & 3) * 8, sA + c0 * 8);
      int c1 = 256 + tid;
      gll16(A + (size_t)(m0 + (c1 >> 2)) * 1024 + k0 + (c1 & 3) * 8, sA + c1 * 8);
      int cb = tid;
      gll16(Bm + (size_t)(n0 + (cb >> 2)) * 1024 + k0 + (cb & 3) * 8, sB + cb * 8);
    }
    __syncthreads();
    bf16x8 af[4], bfv[2];
#pragma unroll
    for (int i = 0; i < 4; i++)
      af[i] = *(const bf16x8*)&sA[(wm * 64 + i * 16 + r) * 32 + qd * 8];
#pragma unroll
    for (int j = 0; j < 2; j++)
      bfv[j] = *(const bf16x8*)&sB[(wn * 32 + j * 16 + r) * 32 + qd * 8];
#pragma unroll
    for (int i = 0; i < 4; i++)
#pragma unroll
      for (int j = 0; j < 2; j++)
        acc[i][j] = __builtin_amdgcn_mfma_f32_16x16x32_bf16(af[i], bfv[j], acc[i][j], 0, 0, 0);
  }
  const int f = flags[0];
#pragma unroll
  for (int i = 0; i < 4; i++)
#pragma unroll
    for (int j = 0; j < 2; j++)
#pragma unroll
      for (int rr = 0; rr < 4; rr++) {
        int row = m0 + wm * 64 + i * 16 + qd * 4 + rr;
        int col = n0 + wn * 32 + j * 16 + r;
        if (f) ((float*)Cout)[(size_t)row * 1024 + col] = acc[i][j][rr];
        else   ((bf16*)Cout)[(size_t)row * 1024 + col] = (bf16)acc[i][j][rr];
      }
}

// ---------------- flash attention: S^T trick, NO split-K, no-max softmax ----------------
// QK computed TRANSPOSED (A=K, B=Q): lane's 4 regs = 4 consecutive KEYS for one q-row
// -> P written as bf16x4 ds_write_b64 straight into A-operand layout. Mask = 1 nibble
// per (i,j) per lane. Q pre-scaled by 0.125*log2(e): exp(score)=2^S.
//
// v5: 8 waves x 16 q-rows (512 threads) share the same 512-block decomposition:
// identical total MFMA/exp/staging per CU, but 4 waves/SIMD resident (vs 2) to
// cover the MFMA->exp->LDS->MFMA dependency chain. Per-thread vmem per tile =
// 1 K-gll16 + 1 V-gll16 + 1 mask load = 3 -> counted wait vmcnt(3).
// XCD-group swizzle keeps all 16 q-blocks of one (b,h) on one XCD (T1).
__global__ __launch_bounds__(512, 4) void attn_kernel(const bf16* __restrict__ Q,
                                                      const bf16* __restrict__ Kp,
                                                      const bf16* __restrict__ Vt,
                                                      const unsigned* __restrict__ bitsT,
                                                      bf16* __restrict__ CTX) {
  __shared__ bf16 sK[2][64 * 64];    // [buf][key][d], chunk-swizzled
  __shared__ bf16 sVT[2][64 * 64];   // [buf][d][key], chunk-swizzled
  __shared__ bf16 sP[128 * 72];      // [q][key], wave-private rows
  const int tid = threadIdx.x;
  const int w = tid >> 6, lane = tid & 63, qd = lane >> 4, r = lane & 15;
  // XCD-group swizzle: wgid%8 = XCD (round-robin dispatch). Group g=(b,h) of 16
  // q-blocks must share one XCD: g = (wgid>>7)*8 + (wgid&7), qb = (wgid>>3)&15.
  const int wgid = blockIdx.x;
  const int bh = ((wgid >> 7) << 3) + (wgid & 7);   // 0..31
  const int b = bh >> 4, h = bh & 15;
  const int q0 = ((wgid >> 3) & 15) * 128;
  const int qrow = w * 16 + r;                      // this lane's q-row (0..127)

  bf16x8 qf[2];
#pragma unroll
  for (int ks = 0; ks < 2; ks++)
    qf[ks] = *(const bf16x8*)(Q + (size_t)(b * L_ + q0 + qrow) * D_ +
                              h * HD_ + ks * 32 + qd * 8);

  bf16x8 ones;
#pragma unroll
  for (int e = 0; e < 8; e++) ones[e] = (bf16)1.0f;

  f32x4 o[4], lacc;
#pragma unroll
  for (int dj = 0; dj < 4; dj++) o[dj] = (f32x4){0.f, 0.f, 0.f, 0.f};
  lacc = (f32x4){0.f, 0.f, 0.f, 0.f};

#define STAGE_KV(KT, KB, VB)                                                      \
  {                                                                               \
    int row = tid >> 3, kc = tid & 7;                                             \
    int kcg = kc ^ (row & 7);                                                     \
    gll16(Kp + (size_t)(b * L_ + (KT) * 64 + row) * D_ + h * HD_ + kcg * 8,       \
          (KB) + tid * 8);                                                        \
    gll16(Vt + (size_t)(bh * 64 + row) * L_ + (KT) * 64 + kcg * 8, (VB) + tid * 8); \
  }

#define MLOAD(KT, M0)                                                             \
  M0 = *(const uint2*)(bitsT + ((size_t)(KT) * 4096 + b * 2048 + q0 + qrow) * 2);

  // prologue: stage tile 0 into buf 0, load its mask (3 vmem ops in flight)
  STAGE_KV(0, &sK[0][0], &sVT[0][0]);
  uint2 mc, mn;
  MLOAD(0, mc);
  mn = mc;

#pragma unroll 2
  for (int it = 0; it < 32; ++it) {
    const bf16* kb = &sK[it & 1][0];
    const bf16* vb = &sVT[it & 1][0];

    if (it < 31) {
      // issue next tile's 3 vmem ops BEFORE waiting: they stay in flight across
      // the barrier and retire under this iteration's compute.
      STAGE_KV(it + 1, &sK[(it + 1) & 1][0], &sVT[(it + 1) & 1][0]);
      MLOAD(it + 1, mn);
      asm volatile("s_waitcnt vmcnt(3)" ::: "memory");   // tile it's 3 ops done
    } else {
      asm volatile("s_waitcnt vmcnt(0)" ::: "memory");
    }
    __builtin_amdgcn_sched_barrier(0);
    __builtin_amdgcn_s_barrier();     // all waves staged tile it

    bf16x8 kf[4][2];
#pragma unroll
    for (int j = 0; j < 4; j++)
#pragma unroll
      for (int ks = 0; ks < 2; ks++) {
        int row = j * 16 + r;
        int phys = (ks * 4 + qd) ^ (row & 7);
        kf[j][ks] = *(const bf16x8*)&kb[row * 64 + phys * 8];
      }

    {
      f32x4 S[4];
      __builtin_amdgcn_s_setprio(1);
#pragma unroll
      for (int j = 0; j < 4; j++) {       // S^T: A=K (m=key), B=Q (n=q)
        S[j] = (f32x4){0.f, 0.f, 0.f, 0.f};
#pragma unroll
        for (int ks = 0; ks < 2; ks++)
          S[j] = __builtin_amdgcn_mfma_f32_16x16x32_bf16(kf[j][ks], qf[ks], S[j], 0, 0, 0);
      }
      __builtin_amdgcn_s_setprio(0);
      // lane holds: q = q0+qrow, keys it*64 + j*16 + qd*4 + rr (rr contiguous!)
#pragma unroll
      for (int j = 0; j < 4; j++) {
        unsigned word = (j < 2) ? mc.x : mc.y;
        unsigned nib = (word >> ((j & 1) * 16 + qd * 4)) & 0xFu;
        bf16x4 pv;
#pragma unroll
        for (int rr = 0; rr < 4; rr++) {
          float e = fast_exp2(S[j][rr]);
          pv[rr] = (bf16)(((nib >> rr) & 1u) ? 0.f : e);
        }
        *(bf16x4*)&sP[qrow * 72 + j * 16 + qd * 4] = pv;
      }
    }
    asm volatile("s_waitcnt lgkmcnt(0)" ::: "memory");  // sP rows are wave-private

    bf16x8 vf[4][2];
#pragma unroll
    for (int dj = 0; dj < 4; dj++)
#pragma unroll
      for (int ks = 0; ks < 2; ks++) {
        int row = dj * 16 + r;
        int phys = (ks * 4 + qd) ^ (row & 7);
        vf[dj][ks] = *(const bf16x8*)&vb[row * 64 + phys * 8];
      }
    __builtin_amdgcn_s_setprio(1);
#pragma unroll
    for (int ks = 0; ks < 2; ks++) {
      bf16x8 pf = *(const bf16x8*)&sP[qrow * 72 + ks * 32 + qd * 8];
#pragma unroll
      for (int dj = 0; dj < 4; dj++)
        o[dj] = __builtin_amdgcn_mfma_f32_16x16x32_bf16(pf, vf[dj][ks], o[dj], 0, 0, 0);
      lacc = __builtin_amdgcn_mfma_f32_16x16x32_bf16(pf, ones, lacc, 0, 0, 0);
    }
    __builtin_amdgcn_s_setprio(0);

    __builtin_amdgcn_s_barrier();     // all waves done reading buf[it&1]
    mc = mn;
  }
#undef STAGE_KV
#undef MLOAD

  // epilogue: divide by row-sum in-register, write final CTX (bf16)
  {
    float inv[4];
#pragma unroll
    for (int rr = 0; rr < 4; rr++) inv[rr] = 1.0f / lacc[rr];
#pragma unroll
    for (int dj = 0; dj < 4; dj++)
#pragma unroll
      for (int rr = 0; rr < 4; rr++) {
        int rg = b * L_ + q0 + w * 16 + qd * 4 + rr;
        int col = h * HD_ + dj * 16 + r;
        CTX[(size_t)rg * 1024 + col] = (bf16)(o[dj][rr] * inv[rr]);
      }
  }
}

// ---------------- launch ----------------
extern "C" void kernel_launch(void* const* d_in, const int* in_sizes, int n_in,
                              void* d_out, int out_size, void* d_ws, size_t ws_size,
                              hipStream_t stream) {
  const void* xq = d_in[0];
  const void* xk = d_in[1];
  const void* xv = d_in[2];
  const void* Wq = d_in[3];
  const void* Wk = d_in[4];
  const void* Wv = d_in[5];
  const void* Wo = d_in[6];
  const void* mask = d_in[7];

  char* ws = (char*)d_ws;
  const size_t MB = 1048576;
  int*      FLAGS = (int*)(ws + 0);
  unsigned* BITS  = (unsigned*)(ws + 4096);          // 1 MB (transposed layout)
  bf16* cWo = (bf16*)(ws + 2 * MB);                  // lives until final GEMM
  bf16* cWq = (bf16*)(ws + 4 * MB);
  bf16* cWk = (bf16*)(ws + 6 * MB);
  bf16* cWv = (bf16*)(ws + 8 * MB);
  bf16* cxq = (bf16*)(ws + 10 * MB);
  bf16* cxk = (bf16*)(ws + 18 * MB);
  bf16* cxv = (bf16*)(ws + 26 * MB);
  bf16* Q   = (bf16*)(ws + 34 * MB);
  bf16* K   = (bf16*)(ws + 42 * MB);
  bf16* VT  = (bf16*)(ws + 50 * MB);
  // cxv region is free after gemm_qkv -> CTX reuses it:
  bf16* CTX = (bf16*)(ws + 26 * MB);    // 8 MB: [4096][1024] bf16

  detect_kernel<<<1, 256, 0, stream>>>((const unsigned short*)xq,
                                       (const unsigned char*)mask, FLAGS);
  canon_pack<<<9216, 256, 0, stream>>>(xq, xk, xv, Wq, Wk, Wv, Wo, mask,
                                       cxq, cxk, cxv, cWq, cWk, cWv, cWo,
                                       BITS, FLAGS);
  gemm_qkv<<<dim3(32, 8, 3), 256, 0, stream>>>(cxq, cWq, Q,
                                               cxk, cWk, K,
                                               cxv, cWv, VT);
  attn_kernel<<<512, 512, 0, stream>>>(Q, K, VT, BITS, CTX);
  gemm_nt_out<<<dim3(32, 16), 256, 0, stream>>>(CTX, cWo, d_out, FLAGS);
}

// Round 5
// 244.624 us; speedup vs baseline: 1.1457x; 1.0354x over previous
//
#include <hip/hip_runtime.h>
#include <hip/hip_bf16.h>

typedef __bf16 bf16;
typedef __attribute__((ext_vector_type(8))) __bf16 bf16x8;
typedef __attribute__((ext_vector_type(4))) __bf16 bf16x4;
typedef __attribute__((ext_vector_type(4))) float f32x4;

#define B_   2
#define L_   2048
#define D_   1024
#define H_   16
#define HD_  64

__device__ __forceinline__ float fast_exp2(float x) {
  float e; asm("v_exp_f32 %0, %1" : "=v"(e) : "v"(x)); return e;
}

// async global->LDS, 16B per lane. LDS dest = wave-uniform base + lane*16.
__device__ __forceinline__ void gll16(const bf16* g, bf16* l) {
  __builtin_amdgcn_global_load_lds((const __attribute__((address_space(1))) void*)g,
                                   (__attribute__((address_space(3))) void*)l,
                                   16, 0, 0);
}

// ---------------- dtype + mask-layout detection ----------------
__global__ void detect_kernel(const unsigned short* __restrict__ q_u,
                              const unsigned char* __restrict__ m_u,
                              int* __restrict__ flags) {
  __shared__ int cnt, odd;
  if (threadIdx.x == 0) { cnt = 0; odd = 0; }
  __syncthreads();
  int c = 0, o = 0;
  for (int i = 0; i < 8; i++) {
    int idx = threadIdx.x * 8 + i;
    unsigned e = (q_u[idx] >> 7) & 0xFF;
    if (e >= 0x8F || (e > 0 && e <= 0x6F)) c++;   // wild exponent
    if ((idx & 3) && m_u[idx]) o = 1;             // nonzero odd byte -> int8 mask
  }
  atomicAdd(&cnt, c);
  if (o) atomicOr(&odd, 1);
  __syncthreads();
  if (threadIdx.x == 0) { flags[0] = (cnt > 128) ? 1 : 0; flags[1] = odd; }
}

// ---------------- canonicalize (7 tensors) + mask bit-pack, ONE launch ----------------
__device__ __forceinline__ void canon_body(const void* src, bf16* dst, int i, int f) {
  if (f) {
    const float4* s = (const float4*)src;
    float4 a = s[i / 4], b2 = s[i / 4 + 1];
    bf16x8 o;
    o[0] = (bf16)a.x;  o[1] = (bf16)a.y;  o[2] = (bf16)a.z;  o[3] = (bf16)a.w;
    o[4] = (bf16)b2.x; o[5] = (bf16)b2.y; o[6] = (bf16)b2.z; o[7] = (bf16)b2.w;
    *(bf16x8*)(dst + i) = o;
  } else {
    *(bf16x8*)(dst + i) = ((const bf16x8*)src)[i / 8];
  }
}

__global__ __launch_bounds__(256) void canon_pack(
    const void* xq, const void* xk, const void* xv,
    const void* Wq, const void* Wk, const void* Wv, const void* Wo,
    const void* mp,
    bf16* cxq, bf16* cxk, bf16* cxv,
    bf16* cWq, bf16* cWk, bf16* cWv, bf16* cWo,
    unsigned* __restrict__ bitsT,
    const int* __restrict__ flags) {
  int t = blockIdx.x;
  if (t >= 8192) {
    // ---- mask pack: bitsT[(kt*4096+row)*2+half], transposed layout ----
    int wid = (t - 8192) * 256 + threadIdx.x;   // one 32-bit word per thread
    unsigned v = 0;
    if (flags[1]) {                              // int8 layout
      const uchar4* p = (const uchar4*)mp;
#pragma unroll
      for (int c = 0; c < 8; c++) {
        uchar4 u = p[wid * 8 + c];
        v |= (u.x ? 1u : 0u) << (c * 4 + 0);
        v |= (u.y ? 1u : 0u) << (c * 4 + 1);
        v |= (u.z ? 1u : 0u) << (c * 4 + 2);
        v |= (u.w ? 1u : 0u) << (c * 4 + 3);
      }
    } else {                                     // int32 layout
      const int4* p = (const int4*)mp;
#pragma unroll
      for (int c = 0; c < 8; c++) {
        int4 u = p[wid * 8 + c];
        v |= (u.x ? 1u : 0u) << (c * 4 + 0);
        v |= (u.y ? 1u : 0u) << (c * 4 + 1);
        v |= (u.z ? 1u : 0u) << (c * 4 + 2);
        v |= (u.w ? 1u : 0u) << (c * 4 + 3);
      }
    }
    int row = wid >> 6, word = wid & 63;
    int kt = word >> 1, half = word & 1;
    bitsT[((size_t)kt * 4096 + row) * 2 + half] = v;
    return;
  }
  const int f = flags[0];
  const void* src; bf16* dst; int base;
  if (t < 2048)      { src = xq; dst = cxq; base = t * 2048; }
  else if (t < 4096) { src = xk; dst = cxk; base = (t - 2048) * 2048; }
  else if (t < 6144) { src = xv; dst = cxv; base = (t - 4096) * 2048; }
  else {
    int w = t - 6144, wi = w >> 9;
    base = (w & 511) * 2048;
    if (wi == 0)      { src = Wq; dst = cWq; }
    else if (wi == 1) { src = Wk; dst = cWk; }
    else if (wi == 2) { src = Wv; dst = cWv; }
    else              { src = Wo; dst = cWo; }
  }
  canon_body(src, dst, base + threadIdx.x * 8, f);
}

// ---------------- fused QKV NT GEMM, 128x128 tile ----------------
// z==0: Q scaled by 0.125*log2(e). z==1: K. z==2: V -> VT transposed per head.
__global__ __launch_bounds__(256) void gemm_qkv(
    const bf16* __restrict__ Aq, const bf16* __restrict__ Bq, bf16* __restrict__ Cq,
    const bf16* __restrict__ Ak, const bf16* __restrict__ Bk, bf16* __restrict__ Ck,
    const bf16* __restrict__ Av, const bf16* __restrict__ Bv, bf16* __restrict__ VT) {
  __shared__ bf16 smem[128 * 136];
  bf16* sA = smem;
  bf16* sB = smem + 4096;
  const int z = blockIdx.z;
  const bf16* A  = (z == 0) ? Aq : (z == 1) ? Ak : Av;
  const bf16* Bm = (z == 0) ? Bq : (z == 1) ? Bk : Bv;

  const int tid = threadIdx.x;
  const int w = tid >> 6, lane = tid & 63, qd = lane >> 4, r = lane & 15;
  const int wm = w >> 1, wn = w & 1;
  const int m0 = blockIdx.x * 128, n0 = blockIdx.y * 128;

  f32x4 acc[4][4];
#pragma unroll
  for (int i = 0; i < 4; i++)
#pragma unroll
    for (int j = 0; j < 4; j++) acc[i][j] = (f32x4){0.f, 0.f, 0.f, 0.f};

  for (int k0 = 0; k0 < 1024; k0 += 32) {
    __syncthreads();
#pragma unroll
    for (int p = 0; p < 2; p++) {
      int c = p * 256 + tid;
      gll16(A + (size_t)(m0 + (c >> 2)) * 1024 + k0 + (c & 3) * 8, sA + c * 8);
    }
#pragma unroll
    for (int p = 0; p < 2; p++) {
      int c = p * 256 + tid;
      gll16(Bm + (size_t)(n0 + (c >> 2)) * 1024 + k0 + (c & 3) * 8, sB + c * 8);
    }
    __syncthreads();
    bf16x8 af[4], bfv[4];
#pragma unroll
    for (int i = 0; i < 4; i++)
      af[i] = *(const bf16x8*)&sA[(wm * 64 + i * 16 + r) * 32 + qd * 8];
#pragma unroll
    for (int j = 0; j < 4; j++)
      bfv[j] = *(const bf16x8*)&sB[(wn * 64 + j * 16 + r) * 32 + qd * 8];
#pragma unroll
    for (int i = 0; i < 4; i++)
#pragma unroll
      for (int j = 0; j < 4; j++)
        acc[i][j] = __builtin_amdgcn_mfma_f32_16x16x32_bf16(af[i], bfv[j], acc[i][j], 0, 0, 0);
  }

  if (z < 2) {
    bf16* C = (z == 0) ? Cq : Ck;
    const float s = (z == 0) ? 0.1803368801f : 1.0f;   // 0.125*log2(e) folded into Q
#pragma unroll
    for (int i = 0; i < 4; i++)
#pragma unroll
      for (int j = 0; j < 4; j++)
#pragma unroll
        for (int rr = 0; rr < 4; rr++) {
          int row = m0 + wm * 64 + i * 16 + qd * 4 + rr;
          int col = n0 + wn * 64 + j * 16 + r;
          C[(size_t)row * 1024 + col] = (bf16)(acc[i][j][rr] * s);
        }
  } else {
    // V transpose epilogue: tile covers 2 heads (BN=128). sT[d_local][token], pad 136.
    __syncthreads();
#pragma unroll
    for (int i = 0; i < 4; i++)
#pragma unroll
      for (int j = 0; j < 4; j++) {
        int col = wn * 64 + j * 16 + r;
        int rowb = wm * 64 + i * 16 + qd * 4;
        bf16x4 v4;
#pragma unroll
        for (int rr = 0; rr < 4; rr++) v4[rr] = (bf16)acc[i][j][rr];
        *(bf16x4*)&smem[col * 136 + rowb] = v4;
      }
    __syncthreads();
    const int b = m0 >> 11, tok0 = m0 & 2047, h0 = n0 >> 6;
#pragma unroll
    for (int p = 0; p < 8; p++) {
      int c = p * 256 + tid;
      int dl = c >> 4, ch = c & 15;
      bf16x8 v = *(const bf16x8*)&smem[dl * 136 + ch * 8];
      int head = h0 + (dl >> 6), d = dl & 63;
      *(bf16x8*)(VT + ((size_t)((b * 16 + head) * 64 + d)) * 2048 + tok0 + ch * 8) = v;
    }
  }
}

// ---------------- output GEMM BM128/BN64 (512 blocks): flagged store ----------------
__global__ __launch_bounds__(256) void gemm_nt_out(const bf16* __restrict__ A,
                                                   const bf16* __restrict__ Bm,
                                                   void* __restrict__ Cout,
                                                   const int* __restrict__ flags) {
  __shared__ bf16 sA[128 * 32];
  __shared__ bf16 sB[64 * 32];
  const int tid = threadIdx.x;
  const int w = tid >> 6, lane = tid & 63, qd = lane >> 4, r = lane & 15;
  const int wm = w >> 1, wn = w & 1;
  const int m0 = blockIdx.x * 128, n0 = blockIdx.y * 64;

  f32x4 acc[4][2];
#pragma unroll
  for (int i = 0; i < 4; i++)
#pragma unroll
    for (int j = 0; j < 2; j++) acc[i][j] = (f32x4){0.f, 0.f, 0.f, 0.f};

  for (int k0 = 0; k0 < 1024; k0 += 32) {
    __syncthreads();
    {
      int c0 = tid;
      gll16(A + (size_t)(m0 + (c0 >> 2)) * 1024 + k0 + (c0 & 3) * 8, sA + c0 * 8);
      int c1 = 256 + tid;
      gll16(A + (size_t)(m0 + (c1 >> 2)) * 1024 + k0 + (c1 & 3) * 8, sA + c1 * 8);
      int cb = tid;
      gll16(Bm + (size_t)(n0 + (cb >> 2)) * 1024 + k0 + (cb & 3) * 8, sB + cb * 8);
    }
    __syncthreads();
    bf16x8 af[4], bfv[2];
#pragma unroll
    for (int i = 0; i < 4; i++)
      af[i] = *(const bf16x8*)&sA[(wm * 64 + i * 16 + r) * 32 + qd * 8];
#pragma unroll
    for (int j = 0; j < 2; j++)
      bfv[j] = *(const bf16x8*)&sB[(wn * 32 + j * 16 + r) * 32 + qd * 8];
#pragma unroll
    for (int i = 0; i < 4; i++)
#pragma unroll
      for (int j = 0; j < 2; j++)
        acc[i][j] = __builtin_amdgcn_mfma_f32_16x16x32_bf16(af[i], bfv[j], acc[i][j], 0, 0, 0);
  }
  const int f = flags[0];
#pragma unroll
  for (int i = 0; i < 4; i++)
#pragma unroll
    for (int j = 0; j < 2; j++)
#pragma unroll
      for (int rr = 0; rr < 4; rr++) {
        int row = m0 + wm * 64 + i * 16 + qd * 4 + rr;
        int col = n0 + wn * 32 + j * 16 + r;
        if (f) ((float*)Cout)[(size_t)row * 1024 + col] = acc[i][j][rr];
        else   ((bf16*)Cout)[(size_t)row * 1024 + col] = (bf16)acc[i][j][rr];
      }
}

// ---------------- flash attention: S^T trick, NO split-K, no-max softmax ----------------
// v6 (T15 att[2] double-pipeline): softmax of tile t-1 is deferred into iteration t,
// where its exp/pack VALU sits adjacent to (and independent of) tile t's QK MFMAs ->
// the two pipes overlap instead of alternating. K/V triple-buffered (stage t+1 over-
// writes buf[(t-2)%3], last read at iter t-1 before its trailing barrier). All state
// rotation (bufs mod 3, S regs mod 2, mask regs mod 3) is STATIC via 6-body unrolled
// groups -- no runtime-indexed arrays (rule #20), no copies of in-flight load regs.
// vmcnt: 3 ops/tile (K gll16 + V gll16 + mask), steady-state 2 tiles in flight,
// counted wait vmcnt(3). 8 waves x 16 q-rows, 512 blocks, XCD-group swizzle (T1).
__global__ __launch_bounds__(512, 4) void attn_kernel(const bf16* __restrict__ Q,
                                                      const bf16* __restrict__ Kp,
                                                      const bf16* __restrict__ Vt,
                                                      const unsigned* __restrict__ bitsT,
                                                      bf16* __restrict__ CTX) {
  __shared__ bf16 sK[3][64 * 64];    // [buf][key][d], chunk-swizzled
  __shared__ bf16 sVT[3][64 * 64];   // [buf][d][key], chunk-swizzled
  __shared__ bf16 sP[128 * 72];      // [q][key], wave-private rows
  const int tid = threadIdx.x;
  const int w = tid >> 6, lane = tid & 63, qd = lane >> 4, r = lane & 15;
  // XCD-group swizzle: wgid%8 = XCD (round-robin dispatch). Group g=(b,h) of 16
  // q-blocks must share one XCD: g = (wgid>>7)*8 + (wgid&7), qb = (wgid>>3)&15.
  const int wgid = blockIdx.x;
  const int bh = ((wgid >> 7) << 3) + (wgid & 7);   // 0..31
  const int b = bh >> 4, h = bh & 15;
  const int q0 = ((wgid >> 3) & 15) * 128;
  const int qrow = w * 16 + r;                      // this lane's q-row (0..127)

  bf16x8 qf[2];
#pragma unroll
  for (int ks = 0; ks < 2; ks++)
    qf[ks] = *(const bf16x8*)(Q + (size_t)(b * L_ + q0 + qrow) * D_ +
                              h * HD_ + ks * 32 + qd * 8);

  bf16x8 ones;
#pragma unroll
  for (int e = 0; e < 8; e++) ones[e] = (bf16)1.0f;

  f32x4 o[4], lacc;
#pragma unroll
  for (int dj = 0; dj < 4; dj++) o[dj] = (f32x4){0.f, 0.f, 0.f, 0.f};
  lacc = (f32x4){0.f, 0.f, 0.f, 0.f};

  f32x4 S_a[4], S_b[4];
  uint2 m0r, m1r, m2r;

#define STAGE_KV(KT, BI)                                                            \
  {                                                                                 \
    int row_ = tid >> 3, kc_ = tid & 7;                                             \
    int kcg_ = kc_ ^ (row_ & 7);                                                    \
    gll16(Kp + (size_t)(b * L_ + (KT) * 64 + row_) * D_ + h * HD_ + kcg_ * 8,       \
          &sK[BI][0] + tid * 8);                                                    \
    gll16(Vt + (size_t)(bh * 64 + row_) * L_ + (KT) * 64 + kcg_ * 8,                \
          &sVT[BI][0] + tid * 8);                                                   \
  }

#define MLOAD(KT, MD)                                                               \
  MD = *(const uint2*)(bitsT + ((size_t)(KT) * 4096 + b * 2048 + q0 + qrow) * 2);

#define QK_BLK(BI, SD)                                                              \
  {                                                                                 \
    __builtin_amdgcn_s_setprio(1);                                                  \
    _Pragma("unroll") for (int j = 0; j < 4; j++) {                                 \
      SD[j] = (f32x4){0.f, 0.f, 0.f, 0.f};                                          \
      _Pragma("unroll") for (int ks = 0; ks < 2; ks++) {                            \
        int row_ = j * 16 + r;                                                      \
        int phys_ = (ks * 4 + qd) ^ (row_ & 7);                                     \
        bf16x8 kf_ = *(const bf16x8*)&sK[BI][row_ * 64 + phys_ * 8];                \
        SD[j] = __builtin_amdgcn_mfma_f32_16x16x32_bf16(kf_, qf[ks], SD[j], 0, 0, 0); \
      }                                                                             \
    }                                                                               \
    __builtin_amdgcn_s_setprio(0);                                                  \
  }

#define EXP_PACK(SP, MP)                                                            \
  {                                                                                 \
    _Pragma("unroll") for (int j = 0; j < 4; j++) {                                 \
      unsigned word_ = ((j) < 2) ? (MP).x : (MP).y;                                 \
      unsigned nib_ = (word_ >> ((j & 1) * 16 + qd * 4)) & 0xFu;                    \
      bf16x4 pv_;                                                                   \
      _Pragma("unroll") for (int rr = 0; rr < 4; rr++) {                            \
        float e_ = fast_exp2((SP)[j][rr]);                                          \
        pv_[rr] = (bf16)(((nib_ >> rr) & 1u) ? 0.f : e_);                           \
      }                                                                             \
      *(bf16x4*)&sP[qrow * 72 + j * 16 + qd * 4] = pv_;                             \
    }                                                                               \
  }

#define PV_BLK(BI)                                                                  \
  {                                                                                 \
    asm volatile("s_waitcnt lgkmcnt(0)" ::: "memory");                              \
    __builtin_amdgcn_sched_barrier(0);                                              \
    bf16x8 vf_[4][2];                                                               \
    _Pragma("unroll") for (int dj = 0; dj < 4; dj++)                                \
      _Pragma("unroll") for (int ks = 0; ks < 2; ks++) {                            \
        int row_ = dj * 16 + r;                                                     \
        int phys_ = (ks * 4 + qd) ^ (row_ & 7);                                     \
        vf_[dj][ks] = *(const bf16x8*)&sVT[BI][row_ * 64 + phys_ * 8];              \
      }                                                                             \
    __builtin_amdgcn_s_setprio(1);                                                  \
    _Pragma("unroll") for (int ks = 0; ks < 2; ks++) {                              \
      bf16x8 pf_ = *(const bf16x8*)&sP[qrow * 72 + ks * 32 + qd * 8];               \
      _Pragma("unroll") for (int dj = 0; dj < 4; dj++)                              \
        o[dj] = __builtin_amdgcn_mfma_f32_16x16x32_bf16(pf_, vf_[dj][ks], o[dj], 0, 0, 0); \
      lacc = __builtin_amdgcn_mfma_f32_16x16x32_bf16(pf_, ones, lacc, 0, 0, 0);     \
    }                                                                               \
    __builtin_amdgcn_s_setprio(0);                                                  \
  }

// one steady-state iteration T: stage T+1, sync tile T, softmax(T-1) || QK(T), PV(T-1)
#define ITER(T, BP, BC, BN, SPV, SCU, MPV, MNX)                                     \
  {                                                                                 \
    STAGE_KV((T) + 1, BN);                                                          \
    MLOAD((T) + 1, MNX);                                                            \
    asm volatile("s_waitcnt vmcnt(3)" ::: "memory");                                \
    __builtin_amdgcn_sched_barrier(0);                                              \
    __builtin_amdgcn_s_barrier();                                                   \
    EXP_PACK(SPV, MPV);                                                             \
    QK_BLK(BC, SCU);                                                                \
    PV_BLK(BP);                                                                     \
    __builtin_amdgcn_s_barrier();                                                   \
  }

  // ---- prologue: tiles 0,1 staged; QK(0) -> S_a ----
  STAGE_KV(0, 0); MLOAD(0, m0r);
  STAGE_KV(1, 1); MLOAD(1, m1r);
  asm volatile("s_waitcnt vmcnt(3)" ::: "memory");   // tile 0 done (tile 1 in flight)
  __builtin_amdgcn_sched_barrier(0);
  __builtin_amdgcn_s_barrier();
  QK_BLK(0, S_a);
  __builtin_amdgcn_s_barrier();

  // ---- main loop T = 1..30, 6-body groups (LCM of buf mod3 and S mod2) ----
  for (int tt = 1; tt <= 25; tt += 6) {
    ITER(tt,     0, 1, 2, S_a, S_b, m0r, m2r);   // T%6==1
    ITER(tt + 1, 1, 2, 0, S_b, S_a, m1r, m0r);   // T%6==2
    ITER(tt + 2, 2, 0, 1, S_a, S_b, m2r, m1r);   // T%6==3
    ITER(tt + 3, 0, 1, 2, S_b, S_a, m0r, m2r);   // T%6==4
    ITER(tt + 4, 1, 2, 0, S_a, S_b, m1r, m0r);   // T%6==5
    ITER(tt + 5, 2, 0, 1, S_b, S_a, m2r, m1r);   // T%6==0
  }

  // ---- T = 31 (no stage; drain vmem) ----
  asm volatile("s_waitcnt vmcnt(0)" ::: "memory");
  __builtin_amdgcn_sched_barrier(0);
  __builtin_amdgcn_s_barrier();
  EXP_PACK(S_a, m0r);     // softmax(30): S from even tile -> S_a, mask(30) in m0r
  QK_BLK(1, S_b);         // QK(31): buf 31%3=1 -> S_b
  PV_BLK(0);              // PV(30): buf 30%3=0
  __builtin_amdgcn_s_barrier();

  // ---- T = 32 drain: softmax(31) + PV(31) only ----
  EXP_PACK(S_b, m1r);     // mask(31) in m[31%3]=m1r
  PV_BLK(1);              // buf 31%3=1

#undef STAGE_KV
#undef MLOAD
#undef QK_BLK
#undef EXP_PACK
#undef PV_BLK
#undef ITER

  // epilogue: divide by row-sum in-register, write final CTX (bf16)
  {
    float inv[4];
#pragma unroll
    for (int rr = 0; rr < 4; rr++) inv[rr] = 1.0f / lacc[rr];
#pragma unroll
    for (int dj = 0; dj < 4; dj++)
#pragma unroll
      for (int rr = 0; rr < 4; rr++) {
        int rg = b * L_ + q0 + w * 16 + qd * 4 + rr;
        int col = h * HD_ + dj * 16 + r;
        CTX[(size_t)rg * 1024 + col] = (bf16)(o[dj][rr] * inv[rr]);
      }
  }
}

// ---------------- launch ----------------
extern "C" void kernel_launch(void* const* d_in, const int* in_sizes, int n_in,
                              void* d_out, int out_size, void* d_ws, size_t ws_size,
                              hipStream_t stream) {
  const void* xq = d_in[0];
  const void* xk = d_in[1];
  const void* xv = d_in[2];
  const void* Wq = d_in[3];
  const void* Wk = d_in[4];
  const void* Wv = d_in[5];
  const void* Wo = d_in[6];
  const void* mask = d_in[7];

  char* ws = (char*)d_ws;
  const size_t MB = 1048576;
  int*      FLAGS = (int*)(ws + 0);
  unsigned* BITS  = (unsigned*)(ws + 4096);          // 1 MB (transposed layout)
  bf16* cWo = (bf16*)(ws + 2 * MB);                  // lives until final GEMM
  bf16* cWq = (bf16*)(ws + 4 * MB);
  bf16* cWk = (bf16*)(ws + 6 * MB);
  bf16* cWv = (bf16*)(ws + 8 * MB);
  bf16* cxq = (bf16*)(ws + 10 * MB);
  bf16* cxk = (bf16*)(ws + 18 * MB);
  bf16* cxv = (bf16*)(ws + 26 * MB);
  bf16* Q   = (bf16*)(ws + 34 * MB);
  bf16* K   = (bf16*)(ws + 42 * MB);
  bf16* VT  = (bf16*)(ws + 50 * MB);
  // cxv region is free after gemm_qkv -> CTX reuses it:
  bf16* CTX = (bf16*)(ws + 26 * MB);    // 8 MB: [4096][1024] bf16

  detect_kernel<<<1, 256, 0, stream>>>((const unsigned short*)xq,
                                       (const unsigned char*)mask, FLAGS);
  canon_pack<<<9216, 256, 0, stream>>>(xq, xk, xv, Wq, Wk, Wv, Wo, mask,
                                       cxq, cxk, cxv, cWq, cWk, cWv, cWo,
                                       BITS, FLAGS);
  gemm_qkv<<<dim3(32, 8, 3), 256, 0, stream>>>(cxq, cWq, Q,
                                               cxk, cWk, K,
                                               cxv, cWv, VT);
  attn_kernel<<<512, 512, 0, stream>>>(Q, K, VT, BITS, CTX);
  gemm_nt_out<<<dim3(32, 16), 256, 0, stream>>>(CTX, cWo, d_out, FLAGS);
}